// Round 1
// baseline (803.252 us; speedup 1.0000x reference)
//
#include <hip/hip_runtime.h>
#include <cstdint>
#include <cfloat>

#define NN 2048
#define DD 128
#define BATCH 8
#define RT 64          // rows per block (K2)
#define MT 64          // cols per tile (K2)
#define STR 130        // padded LDS stride in doubles: 2-way-max bank aliasing (free)

// ---------------- K1: fp64 L2-normalize rows ----------------
__global__ __launch_bounds__(256) void k_normalize(const float* __restrict__ x,
                                                   double* __restrict__ normed) {
  const int wave = threadIdx.x >> 6;
  const int lane = threadIdx.x & 63;
  const long long row = (long long)blockIdx.x * 4 + wave;   // 16384 rows
  float2 v = reinterpret_cast<const float2*>(x + row * DD)[lane];
  const double d0 = (double)v.x, d1 = (double)v.y;
  double s = d0 * d0 + d1 * d1;
  #pragma unroll
  for (int m = 32; m >= 1; m >>= 1) s += __shfl_xor(s, m, 64);
  double denom = sqrt(s);
  denom = denom > 1e-12 ? denom : 1e-12;
  double2 o;
  o.x = d0 / denom;
  o.y = d1 / denom;
  reinterpret_cast<double2*>(normed + row * DD)[lane] = o;
}

// ---------------- K2: zero-fill output + diagonal ----------------
__global__ __launch_bounds__(256) void k_zero_diag(float* __restrict__ out) {
  const long long g = (long long)blockIdx.x * 256 + threadIdx.x;  // float4 id
  const long long p0 = g * 4;
  const int c0 = (int)(p0 & (NN - 1));
  const long long r = p0 >> 11;
  const int n = (int)(r & (NN - 1));
  float4 v;
  v.x = (c0 + 0 == n) ? 1.0f : 0.0f;
  v.y = (c0 + 1 == n) ? 1.0f : 0.0f;
  v.z = (c0 + 2 == n) ? 1.0f : 0.0f;
  v.w = (c0 + 3 == n) ? 1.0f : 0.0f;
  reinterpret_cast<float4*>(out)[g] = v;
}

// Sorted-desc top-8 insertion, tie-break by smaller index (matches jax.lax.top_k).
__device__ __forceinline__ void insert8(double (&v)[8], int (&ix)[8], double nv, int nm) {
  const bool better = (nv > v[7]) || (nv == v[7] && nm < ix[7]);
  if (better) {
    v[7] = nv; ix[7] = nm;
    #pragma unroll
    for (int q = 7; q >= 1; --q) {
      const bool sw = (v[q] > v[q - 1]) || (v[q] == v[q - 1] && ix[q] < ix[q - 1]);
      const double va = v[q - 1], vb = v[q];
      const int ia = ix[q - 1], ib = ix[q];
      v[q - 1] = sw ? vb : va;  v[q] = sw ? va : vb;
      ix[q - 1] = sw ? ib : ia; ix[q] = sw ? ia : ib;
    }
  }
}

// ---------------- K3: fused scores GEMM + top-8 + symmetric scatter ----------------
__global__ __launch_bounds__(256, 1) void k_scores_topk(const double* __restrict__ normed,
                                                        float* __restrict__ out) {
  __shared__ __align__(16) double s_mem[2 * RT * STR];   // 133,120 B
  double* At = s_mem;
  double* Bt = s_mem + RT * STR;

  const int tid  = threadIdx.x;
  const int rgrp = tid >> 4;   // 0..15 -> rows rgrp + 16*i
  const int mg   = tid & 15;   // 0..15 -> cols mg + 16*j (within tile)
  const long long row0 = (long long)blockIdx.x * RT;     // global row base
  const int b = (int)(row0 >> 11);
  const double* Abase = normed + row0 * DD;
  const double* Bbase = normed + ((long long)b * NN) * DD;

  // stage A tile (64 rows x 128), coalesced double2, padded LDS
  #pragma unroll
  for (int i = 0; i < 16; ++i) {
    const int q2 = (tid + i * 256) * 2;
    const int rr = q2 >> 7, kk = q2 & 127;
    const double2 v = *reinterpret_cast<const double2*>(Abase + q2);
    *reinterpret_cast<double2*>(&At[rr * STR + kk]) = v;
  }

  // per-thread top-8 state for 4 rows
  double tv[4][8];
  int ti[4][8];
  #pragma unroll
  for (int i = 0; i < 4; ++i)
    #pragma unroll
    for (int s = 0; s < 8; ++s) { tv[i][s] = -DBL_MAX; ti[i][s] = 0x7fffffff; }

  // prefetch B tile 0 into registers
  double2 pf[16];
  #pragma unroll
  for (int i = 0; i < 16; ++i) {
    const int q2 = (tid + i * 256) * 2;
    pf[i] = *reinterpret_cast<const double2*>(Bbase + q2);
  }

  for (int t = 0; t < NN / MT; ++t) {
    __syncthreads();                      // previous tile's LDS reads complete
    #pragma unroll
    for (int i = 0; i < 16; ++i) {
      const int q2 = (tid + i * 256) * 2;
      const int rr = q2 >> 7, kk = q2 & 127;
      *reinterpret_cast<double2*>(&Bt[rr * STR + kk]) = pf[i];
    }
    __syncthreads();

    if (t + 1 < NN / MT) {                // software-pipelined prefetch
      const double* Bp = Bbase + (long long)(t + 1) * MT * DD;
      #pragma unroll
      for (int i = 0; i < 16; ++i) {
        const int q2 = (tid + i * 256) * 2;
        pf[i] = *reinterpret_cast<const double2*>(Bp + q2);
      }
    }

    double acc[4][4];
    #pragma unroll
    for (int i = 0; i < 4; ++i)
      #pragma unroll
      for (int j = 0; j < 4; ++j) acc[i][j] = 0.0;

    #pragma unroll 4
    for (int kk = 0; kk < DD; kk += 2) {
      double2 a[4], bb[4];
      #pragma unroll
      for (int i = 0; i < 4; ++i)
        a[i] = *reinterpret_cast<const double2*>(&At[(rgrp + 16 * i) * STR + kk]);
      #pragma unroll
      for (int j = 0; j < 4; ++j)
        bb[j] = *reinterpret_cast<const double2*>(&Bt[(mg + 16 * j) * STR + kk]);
      #pragma unroll
      for (int i = 0; i < 4; ++i)
        #pragma unroll
        for (int j = 0; j < 4; ++j) {
          acc[i][j] = fma(a[i].x, bb[j].x, acc[i][j]);
          acc[i][j] = fma(a[i].y, bb[j].y, acc[i][j]);
        }
    }

    const int mbase = t * MT + mg;
    #pragma unroll
    for (int i = 0; i < 4; ++i)
      #pragma unroll
      for (int j = 0; j < 4; ++j)
        insert8(tv[i], ti[i], acc[i][j], mbase + 16 * j);
  }

  // merge 16 per-thread lists per row via LDS
  __syncthreads();
  double* mv = s_mem;                       // [64][16][8] doubles (64 KB)
  int* mi = reinterpret_cast<int*>(s_mem + 8192);  // [64][16][8] ints (32 KB)
  #pragma unroll
  for (int i = 0; i < 4; ++i) {
    const int row = rgrp + 16 * i;
    #pragma unroll
    for (int s = 0; s < 8; ++s) {
      mv[(row * 16 + mg) * 8 + s] = tv[i][s];
      mi[(row * 16 + mg) * 8 + s] = ti[i][s];
    }
  }
  __syncthreads();

  if (tid < RT) {
    const int row = tid;
    double fv[8]; int fi[8];
    #pragma unroll
    for (int s = 0; s < 8; ++s) { fv[s] = -DBL_MAX; fi[s] = 0x7fffffff; }
    for (int c = 0; c < 128; ++c)
      insert8(fv, fi, mv[row * 128 + c], mi[row * 128 + c]);

    const long long rg = row0 + row;           // global row = b*NN + n
    const int n = (int)(rg & (NN - 1));
    const long long batchbase = (rg - n) * NN; // b*NN*NN
    #pragma unroll
    for (int s = 0; s < 8; ++s) {
      const int m = fi[s];
      out[rg * (long long)NN + m] = 1.0f;            // adj[b][n][m] = 1
      out[batchbase + (long long)m * NN + n] = 1.0f; // adj[b][m][n] = 1 (symmetrize)
    }
  }
}

extern "C" void kernel_launch(void* const* d_in, const int* in_sizes, int n_in,
                              void* d_out, int out_size, void* d_ws, size_t ws_size,
                              hipStream_t stream) {
  const float* x = (const float*)d_in[0];
  float* out = (float*)d_out;
  double* normed = (double*)d_ws;   // 16384*128*8 = 16.78 MB

  hipLaunchKernelGGL(k_normalize, dim3(BATCH * NN / 4), dim3(256), 0, stream, x, normed);
  hipLaunchKernelGGL(k_zero_diag, dim3((unsigned)((long long)BATCH * NN * NN / 4 / 256)),
                     dim3(256), 0, stream, out);
  hipLaunchKernelGGL(k_scores_topk, dim3(BATCH * NN / RT), dim3(256), 0, stream, normed, out);
}